// Round 3
// baseline (2826.738 us; speedup 1.0000x reference)
//
#include <hip/hip_runtime.h>
#include <hip/hip_bf16.h>

// CrossWindowAttention3D — round 2: inputs fp32, OUTPUT fp32 (reference output
// dtype is float32; the test label's "bf16" is a hardcoded template string).
// ws: qw|kw|vw|aw, each 512*216*96 fp32 = 42.5 MB (total ~162 MB of d_ws)

#define CH    96
#define DS    48
#define NVOX  (48*48*48)   // 110592
#define WSZ   6
#define NWIN  512
#define NTOK  216
#define NHEADS 4
#define HD    24

// ---- Kernel 1: conv1x1 + shift + window partition -> fp32 window rows ----
__global__ __launch_bounds__(256) void proj_win_kernel(
    const float* __restrict__ x, const float* __restrict__ W,
    const float* __restrict__ b, const int* __restrict__ use_shift,
    float* __restrict__ dst, float scale)
{
    int e = blockIdx.x * 256 + threadIdx.x;       // over NVOX*CH, grid exact
    int voxel = e / CH;
    int oc = e - voxel * CH;
    int d = voxel / (DS * DS);
    int rem = voxel - d * DS * DS;
    int h = rem / DS;
    int w = rem - h * DS;

    int sh = (use_shift[0] != 0) ? 3 : 0;
    int sd = d + sh; if (sd >= DS) sd -= DS;
    int s_h = h + sh; if (s_h >= DS) s_h -= DS;
    int s_w = w + sh; if (s_w >= DS) s_w -= DS;
    int src = (sd * DS + s_h) * DS + s_w;

    float acc = b[oc];
    const float* wrow = W + oc * CH;
#pragma unroll 8
    for (int ic = 0; ic < CH; ic++)
        acc += wrow[ic] * x[ic * NVOX + src];
    acc *= scale;

    int widx = (d / WSZ) * 64 + (h / WSZ) * 8 + (w / WSZ);
    int tok  = (d % WSZ) * 36 + (h % WSZ) * WSZ + (w % WSZ);
    dst[(widx * NTOK + tok) * CH + oc] = acc;
}

// ---- Kernel 2: windowed attention, one block per (window, head) ----
__global__ __launch_bounds__(256) void attn_kernel(
    const float* __restrict__ qw, const float* __restrict__ kw,
    const float* __restrict__ vw, const float* __restrict__ rel_table,
    const int* __restrict__ use_shift, float* __restrict__ aw)
{
    __shared__ float ks[NTOK][HD + 1];     // 21600 B (pad -> conflict-free)
    __shared__ float vs[NTOK][HD + 1];     // 21600 B
    __shared__ float qt[16][HD + 1];       // 1600 B (row tile of q)
    __shared__ float Stile[16][NTOK + 1];  // 13888 B
    __shared__ int   grp[NTOK];            // 864 B
    __shared__ float rinv[16];             // total ~59.6 KB < 64 KB static cap

    int widx = blockIdx.x >> 2;
    int head = blockIdx.x & 3;
    int tid = threadIdx.x;
    bool shift = (use_shift[0] != 0);
    int wd = widx >> 6, wh = (widx >> 3) & 7, ww = widx & 7;

    for (int idx = tid; idx < NTOK * HD; idx += 256) {
        int t = idx / HD, dd = idx - t * HD;
        int g = (widx * NTOK + t) * CH + head * HD + dd;
        ks[t][dd] = kw[g];
        vs[t][dd] = vw[g];
    }
    for (int t = tid; t < NTOK; t += 256) {
        int g = 0;
        if (shift) {
            int td = t / 36, th = (t / 6) % 6, tw = t % 6;
            int cd = wd * 6 + td, chh = wh * 6 + th, cw = ww * 6 + tw;
            int gd = (cd < 42) ? 0 : ((cd < 45) ? 1 : 2);
            int gh = (chh < 42) ? 0 : ((chh < 45) ? 1 : 2);
            int gw = (cw < 42) ? 0 : ((cw < 45) ? 1 : 2);
            g = gd * 9 + gh * 3 + gw;
        }
        grp[t] = g;
    }
    __syncthreads();

    for (int i0 = 0; i0 < NTOK; i0 += 16) {
        int rows = min(16, NTOK - i0);
        // stage q row tile
        for (int idx = tid; idx < rows * HD; idx += 256) {
            int r = idx / HD, dd = idx - r * HD;
            qt[r][dd] = qw[(widx * NTOK + i0 + r) * CH + head * HD + dd];
        }
        __syncthreads();
        // S = q k^T + bias + mask
        for (int e = tid; e < rows * NTOK; e += 256) {
            int r = e / NTOK, j = e - r * NTOK;
            int i = i0 + r;
            float s = 0.f;
#pragma unroll
            for (int dd = 0; dd < HD; dd++) s += qt[r][dd] * ks[j][dd];
            int di = i / 36, hi = (i / 6) % 6, wi = i % 6;
            int dj = j / 36, hj = (j / 6) % 6, wj = j % 6;
            int ridx = ((di - dj + 5) * 11 + (hi - hj + 5)) * 11 + (wi - wj + 5);
            s += rel_table[ridx * NHEADS + head];
            if (grp[i] != grp[j]) s -= 100.f;
            Stile[r][j] = s;
        }
        __syncthreads();
        // softmax rows: 16 threads per row
        {
            int r = tid >> 4, l = tid & 15;
            if (r < rows) {
                float m = -1e30f;
                for (int j = l; j < NTOK; j += 16) m = fmaxf(m, Stile[r][j]);
#pragma unroll
                for (int o = 1; o < 16; o <<= 1) m = fmaxf(m, __shfl_xor(m, o));
                float ssum = 0.f;
                for (int j = l; j < NTOK; j += 16) {
                    float p = __expf(Stile[r][j] - m);
                    Stile[r][j] = p;
                    ssum += p;
                }
#pragma unroll
                for (int o = 1; o < 16; o <<= 1) ssum += __shfl_xor(ssum, o);
                if (l == 0) rinv[r] = 1.f / ssum;
            }
        }
        __syncthreads();
        // O = P V / sum, scatter to original voxel layout
        for (int e = tid; e < rows * HD; e += 256) {
            int r = e / HD, dc = e - r * HD;
            int i = i0 + r;
            float acc = 0.f;
            for (int j = 0; j < NTOK; j++) acc += Stile[r][j] * vs[j][dc];
            acc *= rinv[r];
            int td = i / 36, th = (i / 6) % 6, tw = i % 6;
            int d = wd * 6 + td, h = wh * 6 + th, w = ww * 6 + tw;
            if (shift) {
                d += 3; if (d >= DS) d -= DS;
                h += 3; if (h >= DS) h -= DS;
                w += 3; if (w >= DS) w -= DS;
            }
            int voxel = (d * DS + h) * DS + w;
            aw[voxel * CH + head * HD + dc] = acc;
        }
        __syncthreads();
    }
}

// ---- Kernel 3: output projection, (voxel,ch) fp32 -> (ch,voxel) fp32 ----
__global__ __launch_bounds__(256) void out_proj_kernel(
    const float* __restrict__ aw, const float* __restrict__ Wp,
    const float* __restrict__ bp, float* __restrict__ out)
{
    __shared__ float xs[64][CH + 1];   // pad 97: kills 96-stride bank conflict
    int v0 = blockIdx.x * 64;
    int tid = threadIdx.x;
    for (int li = tid; li < 64 * CH; li += 256) {
        int v = li / CH, ic = li - v * CH;
        xs[v][ic] = aw[(size_t)v0 * CH + li];   // coalesced fp32 reads
    }
    __syncthreads();
    int vl = tid & 63;
    int og = tid >> 6;   // 0..3
    for (int it = 0; it < 24; it++) {
        int oc = og * 24 + it;   // wave-uniform oc -> scalar W reads
        float acc = bp[oc];
        const float* wrow = Wp + oc * CH;
#pragma unroll 8
        for (int ic = 0; ic < CH; ic++)
            acc += wrow[ic] * xs[vl][ic];
        out[oc * NVOX + v0 + vl] = acc;   // coalesced fp32 stores
    }
}

extern "C" void kernel_launch(void* const* d_in, const int* in_sizes, int n_in,
                              void* d_out, int out_size, void* d_ws, size_t ws_size,
                              hipStream_t stream)
{
    const float* q_in = (const float*)d_in[0];
    const float* k_in = (const float*)d_in[1];
    const float* v_in = (const float*)d_in[2];
    const float* Wq   = (const float*)d_in[3];
    const float* bq   = (const float*)d_in[4];
    const float* Wk   = (const float*)d_in[5];
    const float* bk   = (const float*)d_in[6];
    const float* Wv   = (const float*)d_in[7];
    const float* bv   = (const float*)d_in[8];
    const float* Wp   = (const float*)d_in[9];
    const float* bp   = (const float*)d_in[10];
    const float* rel_table = (const float*)d_in[11];
    const int*   use_shift = (const int*)d_in[12];

    const size_t NELEM = (size_t)NWIN * NTOK * CH;   // 10,616,832
    float* qw = (float*)d_ws;
    float* kw = qw + NELEM;
    float* vw = kw + NELEM;
    float* aw = vw + NELEM;

    const float scale = 0.20412414523193154f;  // 1/sqrt(24)
    const int pgrid = NVOX * CH / 256;         // 41472, exact

    proj_win_kernel<<<pgrid, 256, 0, stream>>>(q_in, Wq, bq, use_shift, qw, scale);
    proj_win_kernel<<<pgrid, 256, 0, stream>>>(k_in, Wk, bk, use_shift, kw, 1.0f);
    proj_win_kernel<<<pgrid, 256, 0, stream>>>(v_in, Wv, bv, use_shift, vw, 1.0f);
    attn_kernel<<<NWIN * NHEADS, 256, 0, stream>>>(qw, kw, vw, rel_table, use_shift, aw);
    out_proj_kernel<<<NVOX / 64, 256, 0, stream>>>(aw, Wp, bp, (float*)d_out);
}

// Round 4
// 1096.153 us; speedup vs baseline: 2.5788x; 2.5788x over previous
//
#include <hip/hip_runtime.h>
#include <hip/hip_bf16.h>

// CrossWindowAttention3D — round 3: tiled fp32 GEMM for the 4 projections
// (3x conv1x1+shift+window-partition, 1x output projection).
// attn_kernel is UNCHANGED from the passing round-2 version.
// ws: qw|kw|vw|aw, each 512*216*96 fp32 = 42.5 MB

#define CH    96
#define DS    48
#define NVOX  (48*48*48)   // 110592
#define WSZ   6
#define NWIN  512
#define NTOK  216
#define NHEADS 4
#define HD    24
#define WPAD  100          // padded W row (floats): breaks oc-stride conflicts

// ---- Kernel 1: tiled GEMM: conv1x1 + shift + window partition ----
// Block: 64 shifted-space voxels x 96 out-channels, K=96.
// Xs k-major [96][64] (b128 reads 2-way = free); Ws [96][100] (4 ocgrp -> 4 banks apart).
__global__ __launch_bounds__(256) void proj_gemm_kernel(
    const float* __restrict__ x, const float* __restrict__ W,
    const float* __restrict__ bias, const int* __restrict__ use_shift,
    float* __restrict__ dst, float scale)
{
    __shared__ float Xs[CH][64];     // 24576 B
    __shared__ float Ws[CH][WPAD];   // 38400 B  (total 62976 < 64 KB)
    int tid = threadIdx.x;
    int v0 = blockIdx.x * 64;

    // stage W: coalesced global read, LDS row stride 100
    for (int li = tid; li < CH * CH; li += 256) {
        int oc = li / CH, k = li - oc * CH;
        Ws[oc][k] = W[li];
    }
    // stage X with shift-gather: thread owns voxel vl, loads 24 channels
    {
        int vl = tid & 63;
        int icg = tid >> 6;          // 0..3
        int v = v0 + vl;             // shifted-space linear voxel
        int d = v / (DS * DS);
        int rem = v - d * DS * DS;
        int h = rem / DS;
        int w = rem - h * DS;
        int sh = (use_shift[0] != 0) ? 3 : 0;
        int sd = d + sh; if (sd >= DS) sd -= DS;
        int s_h = h + sh; if (s_h >= DS) s_h -= DS;
        int s_w = w + sh; if (s_w >= DS) s_w -= DS;
        int src = (sd * DS + s_h) * DS + s_w;
        for (int j = 0; j < 24; j++) {
            int ic = icg * 24 + j;
            Xs[ic][vl] = x[ic * NVOX + src];   // coalesced across lanes
        }
    }
    __syncthreads();

    int vgrp = tid & 15;     // voxels 4*vgrp .. +3
    int ocgrp = tid >> 4;    // ocs 6*ocgrp .. +5  (0..15)
    float acc[4][6];
#pragma unroll
    for (int i = 0; i < 4; i++)
#pragma unroll
        for (int j = 0; j < 6; j++) acc[i][j] = 0.f;

    for (int k = 0; k < CH; k += 4) {
        float4 xa = *(const float4*)&Xs[k + 0][4 * vgrp];
        float4 xb = *(const float4*)&Xs[k + 1][4 * vgrp];
        float4 xc = *(const float4*)&Xs[k + 2][4 * vgrp];
        float4 xd = *(const float4*)&Xs[k + 3][4 * vgrp];
#pragma unroll
        for (int oi = 0; oi < 6; oi++) {
            float4 wq = *(const float4*)&Ws[6 * ocgrp + oi][k];
            acc[0][oi] += xa.x * wq.x + xb.x * wq.y + xc.x * wq.z + xd.x * wq.w;
            acc[1][oi] += xa.y * wq.x + xb.y * wq.y + xc.y * wq.z + xd.y * wq.w;
            acc[2][oi] += xa.z * wq.x + xb.z * wq.y + xc.z * wq.z + xd.z * wq.w;
            acc[3][oi] += xa.w * wq.x + xb.w * wq.y + xc.w * wq.z + xd.w * wq.w;
        }
    }

    // store to window layout: dst[(widx*216+tok)*96 + oc] = (acc + b)*scale
#pragma unroll
    for (int vi = 0; vi < 4; vi++) {
        int v = v0 + 4 * vgrp + vi;
        int d = v / (DS * DS);
        int rem = v - d * DS * DS;
        int h = rem / DS;
        int w = rem - h * DS;
        int widx = (d / WSZ) * 64 + (h / WSZ) * 8 + (w / WSZ);
        int tok  = (d % WSZ) * 36 + (h % WSZ) * WSZ + (w % WSZ);
        float* dp = dst + (size_t)(widx * NTOK + tok) * CH + 6 * ocgrp;
#pragma unroll
        for (int oi = 0; oi < 6; oi++)
            dp[oi] = (acc[vi][oi] + bias[6 * ocgrp + oi]) * scale;
    }
}

// ---- Kernel 2: windowed attention (UNCHANGED from passing round) ----
__global__ __launch_bounds__(256) void attn_kernel(
    const float* __restrict__ qw, const float* __restrict__ kw,
    const float* __restrict__ vw, const float* __restrict__ rel_table,
    const int* __restrict__ use_shift, float* __restrict__ aw)
{
    __shared__ float ks[NTOK][HD + 1];
    __shared__ float vs[NTOK][HD + 1];
    __shared__ float qt[16][HD + 1];
    __shared__ float Stile[16][NTOK + 1];
    __shared__ int   grp[NTOK];
    __shared__ float rinv[16];

    int widx = blockIdx.x >> 2;
    int head = blockIdx.x & 3;
    int tid = threadIdx.x;
    bool shift = (use_shift[0] != 0);
    int wd = widx >> 6, wh = (widx >> 3) & 7, ww = widx & 7;

    for (int idx = tid; idx < NTOK * HD; idx += 256) {
        int t = idx / HD, dd = idx - t * HD;
        int g = (widx * NTOK + t) * CH + head * HD + dd;
        ks[t][dd] = kw[g];
        vs[t][dd] = vw[g];
    }
    for (int t = tid; t < NTOK; t += 256) {
        int g = 0;
        if (shift) {
            int td = t / 36, th = (t / 6) % 6, tw = t % 6;
            int cd = wd * 6 + td, chh = wh * 6 + th, cw = ww * 6 + tw;
            int gd = (cd < 42) ? 0 : ((cd < 45) ? 1 : 2);
            int gh = (chh < 42) ? 0 : ((chh < 45) ? 1 : 2);
            int gw = (cw < 42) ? 0 : ((cw < 45) ? 1 : 2);
            g = gd * 9 + gh * 3 + gw;
        }
        grp[t] = g;
    }
    __syncthreads();

    for (int i0 = 0; i0 < NTOK; i0 += 16) {
        int rows = min(16, NTOK - i0);
        for (int idx = tid; idx < rows * HD; idx += 256) {
            int r = idx / HD, dd = idx - r * HD;
            qt[r][dd] = qw[(widx * NTOK + i0 + r) * CH + head * HD + dd];
        }
        __syncthreads();
        for (int e = tid; e < rows * NTOK; e += 256) {
            int r = e / NTOK, j = e - r * NTOK;
            int i = i0 + r;
            float s = 0.f;
#pragma unroll
            for (int dd = 0; dd < HD; dd++) s += qt[r][dd] * ks[j][dd];
            int di = i / 36, hi = (i / 6) % 6, wi = i % 6;
            int dj = j / 36, hj = (j / 6) % 6, wj = j % 6;
            int ridx = ((di - dj + 5) * 11 + (hi - hj + 5)) * 11 + (wi - wj + 5);
            s += rel_table[ridx * NHEADS + head];
            if (grp[i] != grp[j]) s -= 100.f;
            Stile[r][j] = s;
        }
        __syncthreads();
        {
            int r = tid >> 4, l = tid & 15;
            if (r < rows) {
                float m = -1e30f;
                for (int j = l; j < NTOK; j += 16) m = fmaxf(m, Stile[r][j]);
#pragma unroll
                for (int o = 1; o < 16; o <<= 1) m = fmaxf(m, __shfl_xor(m, o));
                float ssum = 0.f;
                for (int j = l; j < NTOK; j += 16) {
                    float p = __expf(Stile[r][j] - m);
                    Stile[r][j] = p;
                    ssum += p;
                }
#pragma unroll
                for (int o = 1; o < 16; o <<= 1) ssum += __shfl_xor(ssum, o);
                if (l == 0) rinv[r] = 1.f / ssum;
            }
        }
        __syncthreads();
        for (int e = tid; e < rows * HD; e += 256) {
            int r = e / HD, dc = e - r * HD;
            int i = i0 + r;
            float acc = 0.f;
            for (int j = 0; j < NTOK; j++) acc += Stile[r][j] * vs[j][dc];
            acc *= rinv[r];
            int td = i / 36, th = (i / 6) % 6, tw = i % 6;
            int d = wd * 6 + td, h = wh * 6 + th, w = ww * 6 + tw;
            if (shift) {
                d += 3; if (d >= DS) d -= DS;
                h += 3; if (h >= DS) h -= DS;
                w += 3; if (w >= DS) w -= DS;
            }
            int voxel = (d * DS + h) * DS + w;
            aw[voxel * CH + head * HD + dc] = acc;
        }
        __syncthreads();
    }
}

// ---- Kernel 3: tiled GEMM output projection: (voxel,ch) -> (ch,voxel) ----
__global__ __launch_bounds__(256) void out_proj_gemm_kernel(
    const float* __restrict__ aw, const float* __restrict__ Wp,
    const float* __restrict__ bp, float* __restrict__ out)
{
    __shared__ float Xs[CH][64];
    __shared__ float Ws[CH][WPAD];
    int tid = threadIdx.x;
    int v0 = blockIdx.x * 64;

    for (int li = tid; li < CH * CH; li += 256) {
        int oc = li / CH, k = li - oc * CH;
        Ws[oc][k] = Wp[li];
    }
    // stage X: lane-per-voxel strided reads (L1-resident 24 KB region)
    for (int li = tid; li < 64 * CH; li += 256) {
        int v = li & 63, ic = li >> 6;
        Xs[ic][v] = aw[(size_t)(v0 + v) * CH + ic];
    }
    __syncthreads();

    int vgrp = tid & 15;
    int ocgrp = tid >> 4;
    float acc[4][6];
#pragma unroll
    for (int i = 0; i < 4; i++)
#pragma unroll
        for (int j = 0; j < 6; j++) acc[i][j] = 0.f;

    for (int k = 0; k < CH; k += 4) {
        float4 xa = *(const float4*)&Xs[k + 0][4 * vgrp];
        float4 xb = *(const float4*)&Xs[k + 1][4 * vgrp];
        float4 xc = *(const float4*)&Xs[k + 2][4 * vgrp];
        float4 xd = *(const float4*)&Xs[k + 3][4 * vgrp];
#pragma unroll
        for (int oi = 0; oi < 6; oi++) {
            float4 wq = *(const float4*)&Ws[6 * ocgrp + oi][k];
            acc[0][oi] += xa.x * wq.x + xb.x * wq.y + xc.x * wq.z + xd.x * wq.w;
            acc[1][oi] += xa.y * wq.x + xb.y * wq.y + xc.y * wq.z + xd.y * wq.w;
            acc[2][oi] += xa.z * wq.x + xb.z * wq.y + xc.z * wq.z + xd.z * wq.w;
            acc[3][oi] += xa.w * wq.x + xb.w * wq.y + xc.w * wq.z + xd.w * wq.w;
        }
    }

#pragma unroll
    for (int oi = 0; oi < 6; oi++) {
        int oc = 6 * ocgrp + oi;
        float bb = bp[oc];
        float* op = out + (size_t)oc * NVOX + v0 + 4 * vgrp;
#pragma unroll
        for (int vi = 0; vi < 4; vi++)
            op[vi] = acc[vi][oi] + bb;
    }
}

extern "C" void kernel_launch(void* const* d_in, const int* in_sizes, int n_in,
                              void* d_out, int out_size, void* d_ws, size_t ws_size,
                              hipStream_t stream)
{
    const float* q_in = (const float*)d_in[0];
    const float* k_in = (const float*)d_in[1];
    const float* v_in = (const float*)d_in[2];
    const float* Wq   = (const float*)d_in[3];
    const float* bq   = (const float*)d_in[4];
    const float* Wk   = (const float*)d_in[5];
    const float* bk   = (const float*)d_in[6];
    const float* Wv   = (const float*)d_in[7];
    const float* bv   = (const float*)d_in[8];
    const float* Wp   = (const float*)d_in[9];
    const float* bp   = (const float*)d_in[10];
    const float* rel_table = (const float*)d_in[11];
    const int*   use_shift = (const int*)d_in[12];

    const size_t NELEM = (size_t)NWIN * NTOK * CH;   // 10,616,832
    float* qw = (float*)d_ws;
    float* kw = qw + NELEM;
    float* vw = kw + NELEM;
    float* aw = vw + NELEM;

    const float scale = 0.20412414523193154f;  // 1/sqrt(24)
    const int ggrid = NVOX / 64;               // 1728

    proj_gemm_kernel<<<ggrid, 256, 0, stream>>>(q_in, Wq, bq, use_shift, qw, scale);
    proj_gemm_kernel<<<ggrid, 256, 0, stream>>>(k_in, Wk, bk, use_shift, kw, 1.0f);
    proj_gemm_kernel<<<ggrid, 256, 0, stream>>>(v_in, Wv, bv, use_shift, vw, 1.0f);
    attn_kernel<<<NWIN * NHEADS, 256, 0, stream>>>(qw, kw, vw, rel_table, use_shift, aw);
    out_proj_gemm_kernel<<<ggrid, 256, 0, stream>>>(aw, Wp, bp, (float*)d_out);
}

// Round 5
// 526.838 us; speedup vs baseline: 5.3655x; 2.0806x over previous
//
#include <hip/hip_runtime.h>
#include <hip/hip_bf16.h>

// CrossWindowAttention3D — round 4: MFMA (bf16) attention.
// proj/out_proj GEMMs unchanged from passing round 3.
// ws: qw|kw|vw|aw (4 x 42.5 MB fp32) + B4 bias table (4x224x224 fp32, 3.2 MB)

#define CH    96
#define DS    48
#define NVOX  (48*48*48)   // 110592
#define WSZ   6
#define NWIN  512
#define NTOK  216
#define NTOKP 224          // padded tokens (14 tiles of 16)
#define NHEADS 4
#define HD    24
#define WPAD  100

typedef __attribute__((ext_vector_type(4))) float  f32x4;
typedef __attribute__((ext_vector_type(4))) short  s16x4;
typedef __attribute__((ext_vector_type(8))) short  s16x8;

static __device__ inline short f2b(float f) {
    union { float f; unsigned u; } v; v.f = f;
    unsigned r = v.u + 0x7FFF + ((v.u >> 16) & 1);   // round-to-nearest-even
    return (short)(r >> 16);
}

// ---- Kernel 1: tiled GEMM: conv1x1 + shift + window partition (unchanged) ----
__global__ __launch_bounds__(256) void proj_gemm_kernel(
    const float* __restrict__ x, const float* __restrict__ W,
    const float* __restrict__ bias, const int* __restrict__ use_shift,
    float* __restrict__ dst, float scale)
{
    __shared__ float Xs[CH][64];
    __shared__ float Ws[CH][WPAD];
    int tid = threadIdx.x;
    int v0 = blockIdx.x * 64;

    for (int li = tid; li < CH * CH; li += 256) {
        int oc = li / CH, k = li - oc * CH;
        Ws[oc][k] = W[li];
    }
    {
        int vl = tid & 63;
        int icg = tid >> 6;
        int v = v0 + vl;
        int d = v / (DS * DS);
        int rem = v - d * DS * DS;
        int h = rem / DS;
        int w = rem - h * DS;
        int sh = (use_shift[0] != 0) ? 3 : 0;
        int sd = d + sh; if (sd >= DS) sd -= DS;
        int s_h = h + sh; if (s_h >= DS) s_h -= DS;
        int s_w = w + sh; if (s_w >= DS) s_w -= DS;
        int src = (sd * DS + s_h) * DS + s_w;
        for (int j = 0; j < 24; j++) {
            int ic = icg * 24 + j;
            Xs[ic][vl] = x[ic * NVOX + src];
        }
    }
    __syncthreads();

    int vgrp = tid & 15;
    int ocgrp = tid >> 4;
    float acc[4][6];
#pragma unroll
    for (int i = 0; i < 4; i++)
#pragma unroll
        for (int j = 0; j < 6; j++) acc[i][j] = 0.f;

    for (int k = 0; k < CH; k += 4) {
        float4 xa = *(const float4*)&Xs[k + 0][4 * vgrp];
        float4 xb = *(const float4*)&Xs[k + 1][4 * vgrp];
        float4 xc = *(const float4*)&Xs[k + 2][4 * vgrp];
        float4 xd = *(const float4*)&Xs[k + 3][4 * vgrp];
#pragma unroll
        for (int oi = 0; oi < 6; oi++) {
            float4 wq = *(const float4*)&Ws[6 * ocgrp + oi][k];
            acc[0][oi] += xa.x * wq.x + xb.x * wq.y + xc.x * wq.z + xd.x * wq.w;
            acc[1][oi] += xa.y * wq.x + xb.y * wq.y + xc.y * wq.z + xd.y * wq.w;
            acc[2][oi] += xa.z * wq.x + xb.z * wq.y + xc.z * wq.z + xd.z * wq.w;
            acc[3][oi] += xa.w * wq.x + xb.w * wq.y + xc.w * wq.z + xd.w * wq.w;
        }
    }

#pragma unroll
    for (int vi = 0; vi < 4; vi++) {
        int v = v0 + 4 * vgrp + vi;
        int d = v / (DS * DS);
        int rem = v - d * DS * DS;
        int h = rem / DS;
        int w = rem - h * DS;
        int widx = (d / WSZ) * 64 + (h / WSZ) * 8 + (w / WSZ);
        int tok  = (d % WSZ) * 36 + (h % WSZ) * WSZ + (w % WSZ);
        float* dp = dst + (size_t)(widx * NTOK + tok) * CH + 6 * ocgrp;
#pragma unroll
        for (int oi = 0; oi < 6; oi++)
            dp[oi] = (acc[vi][oi] + bias[6 * ocgrp + oi]) * scale;
    }
}

// ---- Kernel 1b: precompute bias table B4[h][224][224] (0 in pads) ----
__global__ __launch_bounds__(256) void bias_table_kernel(
    const float* __restrict__ rel_table, float* __restrict__ B4)
{
    int idx = blockIdx.x * 256 + threadIdx.x;   // 4*224*224 = 200704, exact grid
    int h = idx / (NTOKP * NTOKP);
    int rem = idx - h * NTOKP * NTOKP;
    int i = rem / NTOKP;
    int j = rem - i * NTOKP;
    float val = 0.f;
    if (i < NTOK && j < NTOK) {
        int di = i / 36, hi = (i / 6) % 6, wi = i % 6;
        int dj = j / 36, hj = (j / 6) % 6, wj = j % 6;
        int ridx = ((di - dj + 5) * 11 + (hi - hj + 5)) * 11 + (wi - wj + 5);
        val = rel_table[ridx * NHEADS + h];
    }
    B4[idx] = val;
}

// ---- Kernel 2: MFMA windowed attention. One block per (window, head). ----
// LDS: Qs/Ks [224][36] bf16 (stride 72B), Vt [32][248] bf16 (stride 496B),
// Ps per-wave [16][36] bf16 staging, grp [224] int. Total 53.6 KB.
__global__ __launch_bounds__(256) void attn_mfma_kernel(
    const float* __restrict__ qw, const float* __restrict__ kw,
    const float* __restrict__ vw, const float* __restrict__ B4,
    const int* __restrict__ use_shift, float* __restrict__ aw)
{
    __shared__ short Qs[NTOKP * 36];
    __shared__ short Ks[NTOKP * 36];
    __shared__ short Vt[32 * 248];
    __shared__ short Ps[4][16 * 36];
    __shared__ int   grp_s[NTOKP];

    int widx = blockIdx.x >> 2;
    int head = blockIdx.x & 3;
    int tid = threadIdx.x;
    bool shift = (use_shift[0] != 0);
    int wd = widx >> 6, wh = (widx >> 3) & 7, ww = widx & 7;

    // zero-init staged arrays (covers all pads)
    {
        int* z1 = (int*)Qs; int* z2 = (int*)Ks; int* z3 = (int*)Vt;
        for (int i = tid; i < NTOKP * 18; i += 256) { z1[i] = 0; z2[i] = 0; }
        for (int i = tid; i < 32 * 124; i += 256) z3[i] = 0;
    }
    __syncthreads();

    // fill Q,K (bf16), V transposed, grp
    const int hb = head * HD;
    for (int e = tid; e < NTOK * HD; e += 256) {
        int t = e / HD, d = e - t * HD;
        size_t g = (size_t)(widx * NTOK + t) * CH + hb + d;
        Qs[t * 36 + d] = f2b(qw[g]);
        Ks[t * 36 + d] = f2b(kw[g]);
        Vt[d * 248 + t] = f2b(vw[g]);
    }
    for (int t = tid; t < NTOKP; t += 256) {
        int g = 0;
        if (shift && t < NTOK) {
            int td = t / 36, th = (t / 6) % 6, tw = t % 6;
            int cd = wd * 6 + td, chh = wh * 6 + th, cw = ww * 6 + tw;
            int gd = (cd < 42) ? 0 : ((cd < 45) ? 1 : 2);
            int gh = (chh < 42) ? 0 : ((chh < 45) ? 1 : 2);
            int gw = (cw < 42) ? 0 : ((cw < 45) ? 1 : 2);
            g = gd * 9 + gh * 3 + gw;
        }
        grp_s[t] = g;
    }
    __syncthreads();

    const int wid = tid >> 6;
    const int lane = tid & 63;
    const int g = lane >> 4;     // quad 0..3
    const int c = lane & 15;     // col within tile

    const f32x4 zero4 = {0.f, 0.f, 0.f, 0.f};
    short* myPs = &Ps[wid][0];

    for (int mt = wid; mt < 14; mt += 4) {
        int m0 = mt * 16;
        // A-frag: Q rows m0+c, cols g*8..+7
        s16x8 aq;
        {
            const short* p = &Qs[(m0 + c) * 36 + g * 8];
            s16x4 lo = *(const s16x4*)p;
            s16x4 hi = *(const s16x4*)(p + 4);
            aq = __builtin_shufflevector(lo, hi, 0, 1, 2, 3, 4, 5, 6, 7);
        }
        // S row-strip: 14 tiles
        f32x4 sreg[14];
#pragma unroll
        for (int t = 0; t < 14; t++) {
            const short* p = &Ks[(t * 16 + c) * 36 + g * 8];
            s16x4 lo = *(const s16x4*)p;
            s16x4 hi = *(const s16x4*)(p + 4);
            s16x8 bk = __builtin_shufflevector(lo, hi, 0, 1, 2, 3, 4, 5, 6, 7);
            sreg[t] = __builtin_amdgcn_mfma_f32_16x16x32_bf16(aq, bk, zero4, 0, 0, 0);
        }
        // bias + mask + row max
        int gi[4];
        const float* brow[4];
#pragma unroll
        for (int r = 0; r < 4; r++) {
            int i = m0 + g * 4 + r;       // <= 223, always in-bounds of padded tables
            gi[r] = grp_s[i];
            brow[r] = B4 + ((size_t)(head * NTOKP + i)) * NTOKP;
        }
        float mx[4] = {-1e30f, -1e30f, -1e30f, -1e30f};
#pragma unroll
        for (int t = 0; t < 14; t++) {
            int j = t * 16 + c;
            int gj = grp_s[j];
            bool padc = (j >= NTOK);
#pragma unroll
            for (int r = 0; r < 4; r++) {
                float s = sreg[t][r] + brow[r][j];
                if (gi[r] != gj) s -= 100.f;
                if (padc) s = -1e30f;
                sreg[t][r] = s;
                mx[r] = fmaxf(mx[r], s);
            }
        }
#pragma unroll
        for (int o = 1; o < 16; o <<= 1)
#pragma unroll
            for (int r = 0; r < 4; r++) mx[r] = fmaxf(mx[r], __shfl_xor(mx[r], o));
        // exp + row sum
        float sm[4] = {0.f, 0.f, 0.f, 0.f};
#pragma unroll
        for (int t = 0; t < 14; t++)
#pragma unroll
            for (int r = 0; r < 4; r++) {
                float e = __expf(sreg[t][r] - mx[r]);
                sreg[t][r] = e;
                sm[r] += e;
            }
#pragma unroll
        for (int o = 1; o < 16; o <<= 1)
#pragma unroll
            for (int r = 0; r < 4; r++) sm[r] += __shfl_xor(sm[r], o);
        float rinv[4];
#pragma unroll
        for (int r = 0; r < 4; r++) rinv[r] = 1.f / sm[r];

        // PV: 7 k-chunks of 32 tokens, P staged through per-wave LDS tile
        f32x4 o0 = zero4, o1 = zero4;
#pragma unroll 1
        for (int kt = 0; kt < 7; kt++) {
#pragma unroll
            for (int tt = 0; tt < 2; tt++) {
                int t = kt * 2 + tt;
#pragma unroll
                for (int r = 0; r < 4; r++)
                    myPs[(g * 4 + r) * 36 + tt * 16 + c] = f2b(sreg[t][r]);
            }
            // A-frag from Ps: rows c, cols g*8..+7 (same-wave LDS, compiler waits)
            const short* p = &myPs[c * 36 + g * 8];
            s16x4 lo = *(const s16x4*)p;
            s16x4 hi = *(const s16x4*)(p + 4);
            s16x8 ap = __builtin_shufflevector(lo, hi, 0, 1, 2, 3, 4, 5, 6, 7);
            // B-frags from Vt
            const short* pv0 = &Vt[c * 248 + kt * 32 + g * 8];
            s16x4 v0l = *(const s16x4*)pv0;
            s16x4 v0h = *(const s16x4*)(pv0 + 4);
            s16x8 bv0 = __builtin_shufflevector(v0l, v0h, 0, 1, 2, 3, 4, 5, 6, 7);
            const short* pv1 = &Vt[(16 + c) * 248 + kt * 32 + g * 8];
            s16x4 v1l = *(const s16x4*)pv1;
            s16x4 v1h = *(const s16x4*)(pv1 + 4);
            s16x8 bv1 = __builtin_shufflevector(v1l, v1h, 0, 1, 2, 3, 4, 5, 6, 7);
            o0 = __builtin_amdgcn_mfma_f32_16x16x32_bf16(ap, bv0, o0, 0, 0, 0);
            o1 = __builtin_amdgcn_mfma_f32_16x16x32_bf16(ap, bv1, o1, 0, 0, 0);
        }

        // epilogue: scale by 1/sum, scatter to original-voxel (voxel, ch) layout
#pragma unroll
        for (int r = 0; r < 4; r++) {
            int i = m0 + g * 4 + r;
            if (i >= NTOK) continue;
            int td = i / 36, th = (i / 6) % 6, tw = i % 6;
            int d = wd * 6 + td, h = wh * 6 + th, w = ww * 6 + tw;
            if (shift) {
                d += 3; if (d >= DS) d -= DS;
                h += 3; if (h >= DS) h -= DS;
                w += 3; if (w >= DS) w -= DS;
            }
            size_t base = (size_t)((d * DS + h) * DS + w) * CH + hb;
            aw[base + c] = o0[r] * rinv[r];
            if (c < 8) aw[base + 16 + c] = o1[r] * rinv[r];
        }
    }
}

// ---- Kernel 3: tiled GEMM output projection (unchanged) ----
__global__ __launch_bounds__(256) void out_proj_gemm_kernel(
    const float* __restrict__ aw, const float* __restrict__ Wp,
    const float* __restrict__ bp, float* __restrict__ out)
{
    __shared__ float Xs[CH][64];
    __shared__ float Ws[CH][WPAD];
    int tid = threadIdx.x;
    int v0 = blockIdx.x * 64;

    for (int li = tid; li < CH * CH; li += 256) {
        int oc = li / CH, k = li - oc * CH;
        Ws[oc][k] = Wp[li];
    }
    for (int li = tid; li < 64 * CH; li += 256) {
        int v = li & 63, ic = li >> 6;
        Xs[ic][v] = aw[(size_t)(v0 + v) * CH + ic];
    }
    __syncthreads();

    int vgrp = tid & 15;
    int ocgrp = tid >> 4;
    float acc[4][6];
#pragma unroll
    for (int i = 0; i < 4; i++)
#pragma unroll
        for (int j = 0; j < 6; j++) acc[i][j] = 0.f;

    for (int k = 0; k < CH; k += 4) {
        float4 xa = *(const float4*)&Xs[k + 0][4 * vgrp];
        float4 xb = *(const float4*)&Xs[k + 1][4 * vgrp];
        float4 xc = *(const float4*)&Xs[k + 2][4 * vgrp];
        float4 xd = *(const float4*)&Xs[k + 3][4 * vgrp];
#pragma unroll
        for (int oi = 0; oi < 6; oi++) {
            float4 wq = *(const float4*)&Ws[6 * ocgrp + oi][k];
            acc[0][oi] += xa.x * wq.x + xb.x * wq.y + xc.x * wq.z + xd.x * wq.w;
            acc[1][oi] += xa.y * wq.x + xb.y * wq.y + xc.y * wq.z + xd.y * wq.w;
            acc[2][oi] += xa.z * wq.x + xb.z * wq.y + xc.z * wq.z + xd.z * wq.w;
            acc[3][oi] += xa.w * wq.x + xb.w * wq.y + xc.w * wq.z + xd.w * wq.w;
        }
    }

#pragma unroll
    for (int oi = 0; oi < 6; oi++) {
        int oc = 6 * ocgrp + oi;
        float bb = bp[oc];
        float* op = out + (size_t)oc * NVOX + v0 + 4 * vgrp;
#pragma unroll
        for (int vi = 0; vi < 4; vi++)
            op[vi] = acc[vi][oi] + bb;
    }
}

extern "C" void kernel_launch(void* const* d_in, const int* in_sizes, int n_in,
                              void* d_out, int out_size, void* d_ws, size_t ws_size,
                              hipStream_t stream)
{
    const float* q_in = (const float*)d_in[0];
    const float* k_in = (const float*)d_in[1];
    const float* v_in = (const float*)d_in[2];
    const float* Wq   = (const float*)d_in[3];
    const float* bq   = (const float*)d_in[4];
    const float* Wk   = (const float*)d_in[5];
    const float* bk   = (const float*)d_in[6];
    const float* Wv   = (const float*)d_in[7];
    const float* bv   = (const float*)d_in[8];
    const float* Wp   = (const float*)d_in[9];
    const float* bp   = (const float*)d_in[10];
    const float* rel_table = (const float*)d_in[11];
    const int*   use_shift = (const int*)d_in[12];

    const size_t NELEM = (size_t)NWIN * NTOK * CH;   // 10,616,832
    float* qw = (float*)d_ws;
    float* kw = qw + NELEM;
    float* vw = kw + NELEM;
    float* aw = vw + NELEM;
    float* B4 = aw + NELEM;                          // 4*224*224 = 200704 floats

    const float scale = 0.20412414523193154f;  // 1/sqrt(24)
    const int ggrid = NVOX / 64;               // 1728

    bias_table_kernel<<<NHEADS * NTOKP * NTOKP / 256, 256, 0, stream>>>(rel_table, B4);
    proj_gemm_kernel<<<ggrid, 256, 0, stream>>>(q_in, Wq, bq, use_shift, qw, scale);
    proj_gemm_kernel<<<ggrid, 256, 0, stream>>>(k_in, Wk, bk, use_shift, kw, 1.0f);
    proj_gemm_kernel<<<ggrid, 256, 0, stream>>>(v_in, Wv, bv, use_shift, vw, 1.0f);
    attn_mfma_kernel<<<NWIN * NHEADS, 256, 0, stream>>>(qw, kw, vw, B4, use_shift, aw);
    out_proj_gemm_kernel<<<ggrid, 256, 0, stream>>>(aw, Wp, bp, (float*)d_out);
}